// Round 4
// baseline (1275.134 us; speedup 1.0000x reference)
//
#include <hip/hip_runtime.h>
#include <hip/hip_bf16.h>

#define NB 8
#define LSEQ 1024
#define DM 64
#define DFF 256
#define NLAYER 4
#define NROW (NB*LSEQ)

__device__ __forceinline__ float wsum64(float v){
  #pragma unroll
  for (int off = 32; off; off >>= 1) v += __shfl_xor(v, off);
  return v;
}
__device__ __forceinline__ float wmax64(float v){
  #pragma unroll
  for (int off = 32; off; off >>= 1) v = fmaxf(v, __shfl_xor(v, off));
  return v;
}

// ---- copy x -> f32 state ----
__global__ void init_kernel(const float* __restrict__ x, float* __restrict__ xf){
  int i = blockIdx.x * 256 + threadIdx.x;
  xf[i] = x[i];
}

// ---- nz per batch (count protok != 0) ----
__global__ void nz_kernel(const int* __restrict__ protok, float* __restrict__ nz){
  __shared__ float sm[16];
  int t = threadIdx.x;
  float v = (protok[blockIdx.x * LSEQ + t] != 0) ? 1.f : 0.f;
  v = wsum64(v);
  if ((t & 63) == 0) sm[t >> 6] = v;
  __syncthreads();
  if (t < 16){
    float s = sm[t];
    #pragma unroll
    for (int off = 8; off; off >>= 1) s += __shfl_xor(s, off);
    if (t == 0) nz[blockIdx.x] = s;
  }
}

// ---- fused QKV + exact joint-softmax attention, one block per (b,h) ----
// part[k, h*8+d] = sum_q exp(logit(q,k) - m_bh) * v[q,d];  wbuf[bh] = nz_b / S_bh
__global__ __launch_bounds__(256) void qkv_attn(
    const float* __restrict__ xf, const int* __restrict__ protok,
    const float* __restrict__ Wq, const float* __restrict__ bq,
    const float* __restrict__ Wk, const float* __restrict__ bk,
    const float* __restrict__ Wv, const float* __restrict__ bv,
    const float* __restrict__ nz,
    float* __restrict__ part, float* __restrict__ wbuf)
{
  int bh = blockIdx.x, b = bh >> 3, h = bh & 7;
  int t = threadIdx.x;
  __shared__ __align__(16) float Qs[LSEQ][8];   // 32 KB
  __shared__ __align__(16) float Ks[LSEQ][8];   // 32 KB
  __shared__ __align__(16) float Vs[LSEQ][8];   // 32 KB
  __shared__ float Ws[3][64][8];                // 6 KB
  __shared__ __align__(16) float xsg[32][72];   // 9 KB
  __shared__ float red[256];                    // 1 KB

  // stage per-head weight slices
  for (int i = t; i < 512; i += 256) {
    int j = i >> 3, cc = i & 7;
    Ws[0][j][cc] = Wq[j * DM + h * 8 + cc];
    Ws[1][j][cc] = Wk[j * DM + h * 8 + cc];
    Ws[2][j][cc] = Wv[j * DM + h * 8 + cc];
  }
  int cc = t & 7, row = t >> 3;
  float bqv = bq[h * 8 + cc], bkv = bk[h * 8 + cc], bvv = bv[h * 8 + cc];
  __syncthreads();

  // ---- phase A: QKV projection (head slice), 32 chunks of 32 rows ----
  for (int ch = 0; ch < 32; ++ch) {
    int r0 = ch * 32;
    {
      int i = t >> 3, c8 = (t & 7) * 8;
      const float4* p = (const float4*)&xf[((size_t)(b * LSEQ + r0 + i)) * DM + c8];
      float4 p0 = p[0], p1 = p[1];
      *(float4*)&xsg[i][c8]     = p0;
      *(float4*)&xsg[i][c8 + 4] = p1;
    }
    __syncthreads();
    float keep = (protok[b * LSEQ + r0 + row] != 0) ? 1.f : 0.f;
    float aq = bqv, ak = bkv, av = bvv;
    #pragma unroll
    for (int j = 0; j < DM; ++j) {
      float xv = xsg[row][j];
      aq = fmaf(xv, Ws[0][j][cc], aq);
      ak = fmaf(xv, Ws[1][j][cc], ak);
      av = fmaf(xv, Ws[2][j][cc], av);
    }
    int gr = r0 + row;
    Qs[gr][cc] = aq * keep;
    Ks[gr][cc] = ak * keep;
    Vs[gr][cc] = av * keep;
    __syncthreads();
  }

  // ---- phase B: thread owns 4 keys ----
  float kr[4][8], pj[4];
  int k0 = t * 4;
  #pragma unroll
  for (int kk = 0; kk < 4; ++kk) {
    #pragma unroll
    for (int dd = 0; dd < 8; ++dd) kr[kk][dd] = Ks[k0 + kk][dd];
    pj[kk] = (protok[b * LSEQ + k0 + kk] != 0) ? 0.f : -1.0e9f;
  }

  // pass 1: exact max over all (q,k)
  float mt = -3.0e38f;
  for (int q = 0; q < LSEQ; q += 4) {
    float qv[4][8];
    #pragma unroll
    for (int qi = 0; qi < 4; ++qi) {
      float4 a = *(const float4*)&Qs[q + qi][0];
      float4 bb = *(const float4*)&Qs[q + qi][4];
      qv[qi][0]=a.x; qv[qi][1]=a.y; qv[qi][2]=a.z; qv[qi][3]=a.w;
      qv[qi][4]=bb.x; qv[qi][5]=bb.y; qv[qi][6]=bb.z; qv[qi][7]=bb.w;
    }
    #pragma unroll
    for (int qi = 0; qi < 4; ++qi) {
      #pragma unroll
      for (int kk = 0; kk < 4; ++kk) {
        float d = pj[kk];
        #pragma unroll
        for (int dd = 0; dd < 8; ++dd) d = fmaf(qv[qi][dd], kr[kk][dd], d);
        mt = fmaxf(mt, d);
      }
    }
  }
  red[t] = mt; __syncthreads();
  #pragma unroll
  for (int off = 128; off; off >>= 1) {
    if (t < off) red[t] = fmaxf(red[t], red[t + off]);
    __syncthreads();
  }
  float m = red[0];
  __syncthreads();

  // pass 2: exact exp-sum + PV accumulate
  float st = 0.f;
  float acc[4][8] = {};
  for (int q = 0; q < LSEQ; q += 2) {
    float qv[2][8], vv[2][8];
    #pragma unroll
    for (int qi = 0; qi < 2; ++qi) {
      float4 a  = *(const float4*)&Qs[q + qi][0];
      float4 bb = *(const float4*)&Qs[q + qi][4];
      qv[qi][0]=a.x; qv[qi][1]=a.y; qv[qi][2]=a.z; qv[qi][3]=a.w;
      qv[qi][4]=bb.x; qv[qi][5]=bb.y; qv[qi][6]=bb.z; qv[qi][7]=bb.w;
      float4 c0 = *(const float4*)&Vs[q + qi][0];
      float4 c1 = *(const float4*)&Vs[q + qi][4];
      vv[qi][0]=c0.x; vv[qi][1]=c0.y; vv[qi][2]=c0.z; vv[qi][3]=c0.w;
      vv[qi][4]=c1.x; vv[qi][5]=c1.y; vv[qi][6]=c1.z; vv[qi][7]=c1.w;
    }
    #pragma unroll
    for (int qi = 0; qi < 2; ++qi) {
      float e[4];
      #pragma unroll
      for (int kk = 0; kk < 4; ++kk) {
        float d = pj[kk];
        #pragma unroll
        for (int dd = 0; dd < 8; ++dd) d = fmaf(qv[qi][dd], kr[kk][dd], d);
        e[kk] = __expf(d - m);
        st += e[kk];
      }
      #pragma unroll
      for (int kk = 0; kk < 4; ++kk)
        #pragma unroll
        for (int dd = 0; dd < 8; ++dd)
          acc[kk][dd] = fmaf(e[kk], vv[qi][dd], acc[kk][dd]);
    }
  }
  red[t] = st; __syncthreads();
  #pragma unroll
  for (int off = 128; off; off >>= 1) {
    if (t < off) red[t] += red[t + off];
    __syncthreads();
  }
  if (t == 0) wbuf[bh] = nz[b] / red[0];

  #pragma unroll
  for (int kk = 0; kk < 4; ++kk) {
    float* dst = &part[((size_t)(b * LSEQ + k0 + kk)) * DM + h * 8];
    *(float4*)dst       = make_float4(acc[kk][0], acc[kk][1], acc[kk][2], acc[kk][3]);
    *(float4*)(dst + 4) = make_float4(acc[kk][4], acc[kk][5], acc[kk][6], acc[kk][7]);
  }
}

// ---- O-proj + residual + LN1; po is part on input, out1 on output (aliased) ----
__global__ __launch_bounds__(256) void oproj_ln(
    float* po, const float* __restrict__ wbuf,
    const float* __restrict__ Wo, const float* __restrict__ bo,
    const float* __restrict__ xf, const float* __restrict__ g,
    const float* __restrict__ be, const int* __restrict__ protok)
{
  int tid = threadIdx.x, rl = tid >> 6, c = tid & 63;
  int r = blockIdx.x * 4 + rl;
  float gmax = wmax64(wbuf[c]);
  int bh = ((r >> 10) << 3) + (c >> 3);
  float cs = wbuf[bh] / gmax;
  __shared__ float As[4][64];
  As[rl][c] = po[(size_t)r * DM + c] * cs;
  __syncthreads();
  float acc = bo[c];
  #pragma unroll
  for (int j = 0; j < DM; ++j) acc = fmaf(As[rl][j], Wo[j * DM + c], acc);
  float keep = (protok[r] != 0) ? 1.f : 0.f;
  float v = xf[(size_t)r * DM + c] + acc * keep;
  float mu = wsum64(v) * 0.015625f;
  float d = v - mu;
  float var = wsum64(d * d) * 0.015625f;
  float o = d * rsqrtf(var + 1e-9f) * g[c] + be[c];
  po[(size_t)r * DM + c] = o * keep;
}

// ---- fused FFN (h1 in LDS) + residual + LN2 -> new x state ----
__global__ __launch_bounds__(256) void ffn_ln(
    const float* __restrict__ out1,
    const float* __restrict__ W1, const float* __restrict__ b1,
    const float* __restrict__ W2, const float* __restrict__ b2,
    const float* __restrict__ g, const float* __restrict__ be,
    const int* __restrict__ protok, float* __restrict__ xf)
{
  int tid = threadIdx.x, rl = tid >> 6, c = tid & 63;
  int r = blockIdx.x * 4 + rl;
  __shared__ float xs[4][64];
  __shared__ float h1s[4][DFF];
  xs[rl][c] = out1[(size_t)r * DM + c];
  __syncthreads();
  #pragma unroll
  for (int s = 0; s < 4; ++s) {
    int col = c + 64 * s;
    float a = b1[col];
    #pragma unroll
    for (int j = 0; j < DM; ++j) a = fmaf(xs[rl][j], W1[j * DFF + col], a);
    h1s[rl][col] = fmaxf(a, 0.f);
  }
  __syncthreads();
  float a2 = b2[c];
  #pragma unroll 8
  for (int j = 0; j < DFF; ++j) a2 = fmaf(h1s[rl][j], W2[j * DM + c], a2);
  float keep = (protok[r] != 0) ? 1.f : 0.f;
  float v = xs[rl][c] + a2 * keep;
  float mu = wsum64(v) * 0.015625f;
  float d = v - mu;
  float var = wsum64(d * d) * 0.015625f;
  float o = d * rsqrtf(var + 1e-9f) * g[c] + be[c];
  xf[(size_t)r * DM + c] = o * keep;
}

// ---- copy state -> f32 output ----
__global__ void epilogue_kernel(const float* __restrict__ xf, float* __restrict__ out){
  int i = blockIdx.x * 256 + threadIdx.x;
  out[i] = xf[i];
}

extern "C" void kernel_launch(void* const* d_in, const int* in_sizes, int n_in,
                              void* d_out, int out_size, void* d_ws, size_t ws_size,
                              hipStream_t stream) {
  const float* x      = (const float*)d_in[0];
  const int*   protok = (const int*)d_in[1];
  const float* Wq = (const float*)d_in[2];  const float* bq = (const float*)d_in[3];
  const float* Wk = (const float*)d_in[4];  const float* bk = (const float*)d_in[5];
  const float* Wv = (const float*)d_in[6];  const float* bv = (const float*)d_in[7];
  const float* Wo = (const float*)d_in[8];  const float* bo = (const float*)d_in[9];
  const float* W1 = (const float*)d_in[10]; const float* b1 = (const float*)d_in[11];
  const float* W2 = (const float*)d_in[12]; const float* b2 = (const float*)d_in[13];
  const float* g1 = (const float*)d_in[14]; const float* be1 = (const float*)d_in[15];
  const float* g2 = (const float*)d_in[16]; const float* be2 = (const float*)d_in[17];

  const size_t N = (size_t)NROW * DM;   // 524288
  float* xf   = (float*)d_ws;           // N   (x state)
  float* po   = xf + N;                 // N   (attn part -> out1, aliased)
  float* nzb  = po + N;                 // NB
  float* wbuf = nzb + NB;               // 64
  // ws use: 2N + 72 floats ~= 4.19 MB

  init_kernel<<<NROW * DM / 256, 256, 0, stream>>>(x, xf);
  nz_kernel<<<NB, 1024, 0, stream>>>(protok, nzb);

  for (int l = 0; l < NLAYER; ++l) {
    const float* Wq_l = Wq + (size_t)l * DM * DM;  const float* bq_l = bq + (size_t)l * DM;
    const float* Wk_l = Wk + (size_t)l * DM * DM;  const float* bk_l = bk + (size_t)l * DM;
    const float* Wv_l = Wv + (size_t)l * DM * DM;  const float* bv_l = bv + (size_t)l * DM;
    const float* Wo_l = Wo + (size_t)l * DM * DM;  const float* bo_l = bo + (size_t)l * DM;
    const float* W1_l = W1 + (size_t)l * DM * DFF; const float* b1_l = b1 + (size_t)l * DFF;
    const float* W2_l = W2 + (size_t)l * DFF * DM; const float* b2_l = b2 + (size_t)l * DM;
    const float* g1_l = g1 + (size_t)l * DM;  const float* be1_l = be1 + (size_t)l * DM;
    const float* g2_l = g2 + (size_t)l * DM;  const float* be2_l = be2 + (size_t)l * DM;

    qkv_attn<<<64, 256, 0, stream>>>(xf, protok, Wq_l, bq_l, Wk_l, bk_l, Wv_l, bv_l,
                                     nzb, po, wbuf);
    oproj_ln<<<NROW / 4, 256, 0, stream>>>(po, wbuf, Wo_l, bo_l, xf, g1_l, be1_l, protok);
    ffn_ln<<<NROW / 4, 256, 0, stream>>>(po, W1_l, b1_l, W2_l, b2_l, g2_l, be2_l, protok, xf);
  }

  epilogue_kernel<<<NROW * DM / 256, 256, 0, stream>>>(xf, (float*)d_out);
}

// Round 5
// 917.701 us; speedup vs baseline: 1.3895x; 1.3895x over previous
//
#include <hip/hip_runtime.h>

#define NB 8
#define LSEQ 1024
#define DM 64
#define DFF 256
#define NLAYER 4
#define NROW (NB*LSEQ)

__device__ __forceinline__ float wsum64(float v){
  #pragma unroll
  for (int off = 32; off; off >>= 1) v += __shfl_xor(v, off);
  return v;
}
__device__ __forceinline__ float wmax64(float v){
  #pragma unroll
  for (int off = 32; off; off >>= 1) v = fmaxf(v, __shfl_xor(v, off));
  return v;
}

// ---- nz per batch ----
__global__ void nz_kernel(const int* __restrict__ protok, float* __restrict__ nz){
  __shared__ float sm[16];
  int t = threadIdx.x;
  float v = (protok[blockIdx.x * LSEQ + t] != 0) ? 1.f : 0.f;
  v = wsum64(v);
  if ((t & 63) == 0) sm[t >> 6] = v;
  __syncthreads();
  if (t < 16){
    float s = sm[t];
    #pragma unroll
    for (int off = 8; off; off >>= 1) s += __shfl_xor(s, off);
    if (t == 0) nz[blockIdx.x] = s;
  }
}

// LDS pool offsets (floats)
#define QS_OFF   0        // [1024][8]
#define VS_OFF   8192     // [1024][8]
#define KS_OFF   16384    // [256][8]
#define XSG_OFF  18432    // [32][72]
#define WS_OFF   20736    // [3][64][8]
#define RED_OFF  22272    // [256]
#define POOL_SZ  22528    // 88 KB

// ---- fused QKV + joint-softmax attention, block = (bh, kc of 256 keys) ----
// part[k, h*8+d] = sum_q exp(l(q,k) - mhat_blk) v[q,d];  plus (mhat, mu_true, s) per block
__global__ __launch_bounds__(256) void qkv_attn(
    const float* __restrict__ xin, const int* __restrict__ protok,
    const float* __restrict__ Wq, const float* __restrict__ bq,
    const float* __restrict__ Wk, const float* __restrict__ bk,
    const float* __restrict__ Wv, const float* __restrict__ bv,
    float* __restrict__ part, float* __restrict__ mh_out,
    float* __restrict__ mt_out, float* __restrict__ s_out)
{
  int blk = blockIdx.x, bh = blk >> 2, kc = blk & 3;
  int b = bh >> 3, h = bh & 7;
  int t = threadIdx.x;
  __shared__ __align__(16) float pool[POOL_SZ];
  float* red = pool + RED_OFF;

  // stage weight head-slices
  for (int i = t; i < 512; i += 256) {
    int jj = i >> 3, c8 = i & 7;
    pool[WS_OFF + i]        = Wq[jj * DM + h * 8 + c8];
    pool[WS_OFF + 512 + i]  = Wk[jj * DM + h * 8 + c8];
    pool[WS_OFF + 1024 + i] = Wv[jj * DM + h * 8 + c8];
  }
  int cc = t & 7, prow = t >> 3;
  float bqv = bq[h*8+cc], bkv = bk[h*8+cc], bvv = bv[h*8+cc];
  __syncthreads();

  // ---- projection: Q,V all 1024 rows; K own 256 rows; row-norm maxima ----
  float qn2max = 0.f, kn2max = 0.f;
  for (int ch = 0; ch < 32; ++ch) {
    int r0 = ch * 32;
    {
      int i = t >> 3, c8 = (t & 7) * 8;
      const float4* p = (const float4*)&xin[((size_t)(b*LSEQ + r0 + i))*DM + c8];
      float4 p0 = p[0], p1 = p[1];
      *(float4*)&pool[XSG_OFF + i*72 + c8]     = p0;
      *(float4*)&pool[XSG_OFF + i*72 + c8 + 4] = p1;
    }
    __syncthreads();
    float keep = (protok[b*LSEQ + r0 + prow] != 0) ? 1.f : 0.f;
    float aq = bqv, av = bvv;
    #pragma unroll
    for (int jj = 0; jj < DM; ++jj) {
      float xv = pool[XSG_OFF + prow*72 + jj];
      aq = fmaf(xv, pool[WS_OFF + jj*8 + cc], aq);
      av = fmaf(xv, pool[WS_OFF + 1024 + jj*8 + cc], av);
    }
    aq *= keep; av *= keep;
    int gr = r0 + prow;
    pool[QS_OFF + gr*8 + cc] = aq;
    pool[VS_OFF + gr*8 + cc] = av;
    float s2 = aq * aq;
    s2 += __shfl_xor(s2, 1); s2 += __shfl_xor(s2, 2); s2 += __shfl_xor(s2, 4);
    qn2max = fmaxf(qn2max, s2);
    if ((ch >> 3) == kc) {
      float ak = bkv;
      #pragma unroll
      for (int jj = 0; jj < DM; ++jj)
        ak = fmaf(pool[XSG_OFF + prow*72 + jj], pool[WS_OFF + 512 + jj*8 + cc], ak);
      ak *= keep;
      pool[KS_OFF + (gr - kc*256)*8 + cc] = ak;
      float k2 = ak * ak;
      k2 += __shfl_xor(k2, 1); k2 += __shfl_xor(k2, 2); k2 += __shfl_xor(k2, 4);
      kn2max = fmaxf(kn2max, k2);
    }
    __syncthreads();
  }

  // Cauchy-Schwarz logit upper bound mhat = max|q| * max|k|
  red[t] = qn2max; __syncthreads();
  #pragma unroll
  for (int off = 128; off; off >>= 1){ if (t < off) red[t] = fmaxf(red[t], red[t+off]); __syncthreads(); }
  float qn2 = red[0]; __syncthreads();
  red[t] = kn2max; __syncthreads();
  #pragma unroll
  for (int off = 128; off; off >>= 1){ if (t < off) red[t] = fmaxf(red[t], red[t+off]); __syncthreads(); }
  float kn2 = red[0]; __syncthreads();
  float mhat = sqrtf(qn2 * kn2);

  // ---- single pass: thread = (key-group g of 8 keys, q-chunk j of 128 q) ----
  int g = t & 31, j = t >> 5;
  float kr[8][8], pj[8];
  #pragma unroll
  for (int kk = 0; kk < 8; ++kk) {
    #pragma unroll
    for (int dd = 0; dd < 8; ++dd) kr[kk][dd] = pool[KS_OFF + (g*8+kk)*8 + dd];
    pj[kk] = (protok[b*LSEQ + kc*256 + g*8 + kk] != 0) ? 0.f : -1.0e9f;
  }

  float acc[8][8] = {};
  float st = 0.f, mu_sh = -3.0e38f;
  int q0 = j * 128;
  for (int q = q0; q < q0 + 128; ++q) {
    float4 a  = *(const float4*)&pool[QS_OFF + q*8];
    float4 b4 = *(const float4*)&pool[QS_OFF + q*8 + 4];
    float4 c0 = *(const float4*)&pool[VS_OFF + q*8];
    float4 c1 = *(const float4*)&pool[VS_OFF + q*8 + 4];
    float qv[8] = {a.x,a.y,a.z,a.w,b4.x,b4.y,b4.z,b4.w};
    float vv[8] = {c0.x,c0.y,c0.z,c0.w,c1.x,c1.y,c1.z,c1.w};
    #pragma unroll
    for (int kk = 0; kk < 8; ++kk) {
      float d = pj[kk] - mhat;
      #pragma unroll
      for (int dd = 0; dd < 8; ++dd) d = fmaf(qv[dd], kr[kk][dd], d);
      mu_sh = fmaxf(mu_sh, d);
      float e = __expf(d);
      st += e;
      #pragma unroll
      for (int dd = 0; dd < 8; ++dd) acc[kk][dd] = fmaf(e, vv[dd], acc[kk][dd]);
    }
  }
  __syncthreads();

  // block reductions: true max (shifted) and exp-sum
  red[t] = mu_sh; __syncthreads();
  #pragma unroll
  for (int off = 128; off; off >>= 1){ if (t < off) red[t] = fmaxf(red[t], red[t+off]); __syncthreads(); }
  float mu_blk = red[0] + mhat; __syncthreads();
  red[t] = st; __syncthreads();
  #pragma unroll
  for (int off = 128; off; off >>= 1){ if (t < off) red[t] += red[t+off]; __syncthreads(); }
  if (t == 0) { s_out[blk] = red[0]; mh_out[blk] = mhat; mt_out[blk] = mu_blk; }
  __syncthreads();

  // merge acc across the 8 q-chunk threads per key-group (tree via pool[0..16384))
  float* a4 = &acc[0][0];
  if (j >= 4) {
    #pragma unroll
    for (int i = 0; i < 16; ++i) *(float4*)&pool[t*64 + i*4] = *(float4*)&a4[i*4];
  }
  __syncthreads();
  if (j < 4) {
    #pragma unroll
    for (int i = 0; i < 64; ++i) a4[i] += pool[(t+128)*64 + i];
  }
  __syncthreads();
  if (j == 2 || j == 3) {
    #pragma unroll
    for (int i = 0; i < 16; ++i) *(float4*)&pool[t*64 + i*4] = *(float4*)&a4[i*4];
  }
  __syncthreads();
  if (j < 2) {
    #pragma unroll
    for (int i = 0; i < 64; ++i) a4[i] += pool[(t+64)*64 + i];
  }
  __syncthreads();
  if (j == 1) {
    #pragma unroll
    for (int i = 0; i < 16; ++i) *(float4*)&pool[t*64 + i*4] = *(float4*)&a4[i*4];
  }
  __syncthreads();
  if (j == 0) {
    #pragma unroll
    for (int i = 0; i < 64; ++i) a4[i] += pool[(t+32)*64 + i];
    // redistribute merged rows into pool[0..2048) for coalesced store
    #pragma unroll
    for (int kk = 0; kk < 8; ++kk) {
      *(float4*)&pool[(g*8+kk)*8]     = *(float4*)&acc[kk][0];
      *(float4*)&pool[(g*8+kk)*8 + 4] = *(float4*)&acc[kk][4];
    }
  }
  __syncthreads();
  float* dst = &part[((size_t)(b*LSEQ + kc*256 + t))*DM + h*8];
  *(float4*)dst     = *(float4*)&pool[t*8];
  *(float4*)(dst+4) = *(float4*)&pool[t*8 + 4];
}

// ---- combine: per bh true max + S; cs[kc][bh] ----
__global__ void attn_combine(const float* __restrict__ mh, const float* __restrict__ mt,
                             const float* __restrict__ sp, const float* __restrict__ nz,
                             float* __restrict__ cs){
  int bh = threadIdx.x;
  float mhl[4], sl[4];
  float mu = -3.0e38f;
  #pragma unroll
  for (int i = 0; i < 4; ++i) {
    mhl[i] = mh[bh*4+i]; sl[i] = sp[bh*4+i];
    mu = fmaxf(mu, mt[bh*4+i]);
  }
  float S = 0.f;
  #pragma unroll
  for (int i = 0; i < 4; ++i) S += sl[i] * __expf(mhl[i] - mu);
  float w = nz[bh >> 3] / S;
  float gm = wmax64(w);
  float c = w / gm;
  #pragma unroll
  for (int i = 0; i < 4; ++i) cs[i*64 + bh] = c * __expf(mhl[i] - mu);
}

// ---- O-proj + residual + LN1 (8 rows/block); po: part in, out1 out ----
__global__ __launch_bounds__(512) void oproj_ln(
    float* po, const float* __restrict__ cs,
    const float* __restrict__ Wo, const float* __restrict__ bo,
    const float* __restrict__ xin, const float* __restrict__ g,
    const float* __restrict__ be, const int* __restrict__ protok)
{
  int tid = threadIdx.x, rl = tid >> 6, c = tid & 63;
  int r = blockIdx.x * 8 + rl;
  int bh = ((r >> 10) << 3) + (c >> 3);
  int kc = (r >> 8) & 3;
  __shared__ float As[8][64];
  As[rl][c] = po[(size_t)r * DM + c] * cs[kc*64 + bh];
  __syncthreads();
  float acc = bo[c];
  #pragma unroll
  for (int jj = 0; jj < DM; ++jj) acc = fmaf(As[rl][jj], Wo[jj * DM + c], acc);
  float keep = (protok[r] != 0) ? 1.f : 0.f;
  float v = xin[(size_t)r * DM + c] + acc * keep;
  float mu = wsum64(v) * 0.015625f;
  float d = v - mu;
  float var = wsum64(d * d) * 0.015625f;
  float o = d * rsqrtf(var + 1e-9f) * g[c] + be[c];
  po[(size_t)r * DM + c] = o * keep;
}

// ---- fused FFN + residual + LN2 (8 rows/block) ----
__global__ __launch_bounds__(512) void ffn_ln(
    const float* __restrict__ out1,
    const float* __restrict__ W1, const float* __restrict__ b1,
    const float* __restrict__ W2, const float* __restrict__ b2,
    const float* __restrict__ g, const float* __restrict__ be,
    const int* __restrict__ protok, float* __restrict__ xout)
{
  int tid = threadIdx.x, rl = tid >> 6, c = tid & 63;
  int r = blockIdx.x * 8 + rl;
  __shared__ float xs[8][64];
  __shared__ float h1s[8][DFF];
  xs[rl][c] = out1[(size_t)r * DM + c];
  __syncthreads();
  #pragma unroll
  for (int s = 0; s < 4; ++s) {
    int col = c + 64 * s;
    float a = b1[col];
    #pragma unroll
    for (int jj = 0; jj < DM; ++jj) a = fmaf(xs[rl][jj], W1[jj * DFF + col], a);
    h1s[rl][col] = fmaxf(a, 0.f);
  }
  __syncthreads();
  float a2 = b2[c];
  #pragma unroll 8
  for (int jj = 0; jj < DFF; ++jj) a2 = fmaf(h1s[rl][jj], W2[jj * DM + c], a2);
  float keep = (protok[r] != 0) ? 1.f : 0.f;
  float v = xs[rl][c] + a2 * keep;
  float mu = wsum64(v) * 0.015625f;
  float d = v - mu;
  float var = wsum64(d * d) * 0.015625f;
  float o = d * rsqrtf(var + 1e-9f) * g[c] + be[c];
  xout[(size_t)r * DM + c] = o * keep;
}

extern "C" void kernel_launch(void* const* d_in, const int* in_sizes, int n_in,
                              void* d_out, int out_size, void* d_ws, size_t ws_size,
                              hipStream_t stream) {
  const float* x      = (const float*)d_in[0];
  const int*   protok = (const int*)d_in[1];
  const float* Wq = (const float*)d_in[2];  const float* bq = (const float*)d_in[3];
  const float* Wk = (const float*)d_in[4];  const float* bk = (const float*)d_in[5];
  const float* Wv = (const float*)d_in[6];  const float* bv = (const float*)d_in[7];
  const float* Wo = (const float*)d_in[8];  const float* bo = (const float*)d_in[9];
  const float* W1 = (const float*)d_in[10]; const float* b1 = (const float*)d_in[11];
  const float* W2 = (const float*)d_in[12]; const float* b2 = (const float*)d_in[13];
  const float* g1 = (const float*)d_in[14]; const float* be1 = (const float*)d_in[15];
  const float* g2 = (const float*)d_in[16]; const float* be2 = (const float*)d_in[17];

  const size_t N = (size_t)NROW * DM;   // 524288
  float* xf   = (float*)d_ws;           // N (state after layers 0..2)
  float* po   = xf + N;                 // N (attn part -> out1, aliased)
  float* nzb  = po + N;                 // 8
  float* mh   = nzb + 8;                // 256
  float* mt   = mh + 256;               // 256
  float* sp   = mt + 256;               // 256
  float* cs   = sp + 256;               // 256
  // ws use: 2N + ~1K floats ~= 4.2 MB

  nz_kernel<<<NB, 1024, 0, stream>>>(protok, nzb);

  for (int l = 0; l < NLAYER; ++l) {
    const float* Wq_l = Wq + (size_t)l * DM * DM;  const float* bq_l = bq + (size_t)l * DM;
    const float* Wk_l = Wk + (size_t)l * DM * DM;  const float* bk_l = bk + (size_t)l * DM;
    const float* Wv_l = Wv + (size_t)l * DM * DM;  const float* bv_l = bv + (size_t)l * DM;
    const float* Wo_l = Wo + (size_t)l * DM * DM;  const float* bo_l = bo + (size_t)l * DM;
    const float* W1_l = W1 + (size_t)l * DM * DFF; const float* b1_l = b1 + (size_t)l * DFF;
    const float* W2_l = W2 + (size_t)l * DFF * DM; const float* b2_l = b2 + (size_t)l * DM;
    const float* g1_l = g1 + (size_t)l * DM;  const float* be1_l = be1 + (size_t)l * DM;
    const float* g2_l = g2 + (size_t)l * DM;  const float* be2_l = be2 + (size_t)l * DM;

    const float* xin = (l == 0) ? x : xf;
    float* xout = (l == NLAYER - 1) ? (float*)d_out : xf;

    qkv_attn<<<256, 256, 0, stream>>>(xin, protok, Wq_l, bq_l, Wk_l, bk_l, Wv_l, bv_l,
                                      po, mh, mt, sp);
    attn_combine<<<1, 64, 0, stream>>>(mh, mt, sp, nzb, cs);
    oproj_ln<<<NROW / 8, 512, 0, stream>>>(po, cs, Wo_l, bo_l, xin, g1_l, be1_l, protok);
    ffn_ln<<<NROW / 8, 512, 0, stream>>>(po, W1_l, b1_l, W2_l, b2_l, g2_l, be2_l, protok, xout);
  }
}

// Round 6
// 617.893 us; speedup vs baseline: 2.0637x; 1.4852x over previous
//
#include <hip/hip_runtime.h>

#define NB 8
#define LSEQ 1024
#define DM 64
#define DFF 256
#define NLAYER 4
#define NROW (NB*LSEQ)

__device__ __forceinline__ float wsum64(float v){
  #pragma unroll
  for (int off = 32; off; off >>= 1) v += __shfl_xor(v, off);
  return v;
}
__device__ __forceinline__ float wmax64(float v){
  #pragma unroll
  for (int off = 32; off; off >>= 1) v = fmaxf(v, __shfl_xor(v, off));
  return v;
}

// ---- nz per batch ----
__global__ void nz_kernel(const int* __restrict__ protok, float* __restrict__ nz){
  __shared__ float sm[16];
  int t = threadIdx.x;
  float v = (protok[blockIdx.x * LSEQ + t] != 0) ? 1.f : 0.f;
  v = wsum64(v);
  if ((t & 63) == 0) sm[t >> 6] = v;
  __syncthreads();
  if (t < 16){
    float s = sm[t];
    #pragma unroll
    for (int off = 8; off; off >>= 1) s += __shfl_xor(s, off);
    if (t == 0) nz[blockIdx.x] = s;
  }
}

// LDS pool offsets (floats)
#define QS_OFF   0        // [1024][8]  = 8192
#define VS_OFF   8192     // [1024][8]  = 8192
#define KS_OFF   16384    // [256][8]   = 2048
#define WS_OFF   18432    // [3][64][8] = 1536
#define XSG_OFF  19968    // [64][72]   = 4608
#define RED_OFF  24576    // [16]
#define POOL_SZ  24608    // ~96.1 KB -> 1 block/CU, 8 waves
// merge region reuses [0 .. 8*2112=16896)

// ---- fused QKV + joint-softmax attention ----
// block = (bh, kc in 0..3); 512 threads: wave j = q-chunk (128 q), lane kgrp = 4 keys.
// part[k, h*8+d] = sum_q exp(l(q,k) - mhat_blk) v[q,d]; per-block (mhat, true max, expsum)
__global__ __launch_bounds__(512) void qkv_attn(
    const float* __restrict__ xin, const int* __restrict__ protok,
    const float* __restrict__ Wq, const float* __restrict__ bq,
    const float* __restrict__ Wk, const float* __restrict__ bk,
    const float* __restrict__ Wv, const float* __restrict__ bv,
    float* __restrict__ part, float* __restrict__ mh_out,
    float* __restrict__ mt_out, float* __restrict__ s_out)
{
  int blk = blockIdx.x, bh = blk >> 2, kc = blk & 3;
  int b = bh >> 3, h = bh & 7;
  int t = threadIdx.x;
  __shared__ __align__(16) float pool[POOL_SZ];

  // stage weight head-slices: t = jj*8 + c8
  {
    int jj = t >> 3, c8 = t & 7;
    pool[WS_OFF + t]        = Wq[jj * DM + h * 8 + c8];
    pool[WS_OFF + 512 + t]  = Wk[jj * DM + h * 8 + c8];
    pool[WS_OFF + 1024 + t] = Wv[jj * DM + h * 8 + c8];
  }
  int cc = t & 7, prow = t >> 3;   // prow 0..63
  float bqv = bq[h*8+cc], bkv = bk[h*8+cc], bvv = bv[h*8+cc];
  __syncthreads();

  // ---- projection: Q,V all 1024 rows; K own 256 rows; track row-norm maxima ----
  float qn2max = 0.f, kn2max = 0.f;
  for (int ch = 0; ch < 16; ++ch) {
    int r0 = ch * 64;
    {
      int i = t >> 3, c8 = (t & 7) * 8;
      const float4* p = (const float4*)&xin[((size_t)(b*LSEQ + r0 + i))*DM + c8];
      float4 p0 = p[0], p1 = p[1];
      *(float4*)&pool[XSG_OFF + i*72 + c8]     = p0;
      *(float4*)&pool[XSG_OFF + i*72 + c8 + 4] = p1;
    }
    __syncthreads();
    float keep = (protok[b*LSEQ + r0 + prow] != 0) ? 1.f : 0.f;
    float aq = bqv, av = bvv;
    #pragma unroll
    for (int jj = 0; jj < DM; ++jj) {
      float xv = pool[XSG_OFF + prow*72 + jj];
      aq = fmaf(xv, pool[WS_OFF + jj*8 + cc], aq);
      av = fmaf(xv, pool[WS_OFF + 1024 + jj*8 + cc], av);
    }
    aq *= keep; av *= keep;
    int gr = r0 + prow;
    pool[QS_OFF + gr*8 + cc] = aq;
    pool[VS_OFF + gr*8 + cc] = av;
    float s2 = aq * aq;
    s2 += __shfl_xor(s2, 1); s2 += __shfl_xor(s2, 2); s2 += __shfl_xor(s2, 4);
    qn2max = fmaxf(qn2max, s2);
    if ((ch >> 2) == kc) {
      float ak = bkv;
      #pragma unroll
      for (int jj = 0; jj < DM; ++jj)
        ak = fmaf(pool[XSG_OFF + prow*72 + jj], pool[WS_OFF + 512 + jj*8 + cc], ak);
      ak *= keep;
      pool[KS_OFF + (gr - kc*256)*8 + cc] = ak;
      float k2 = ak * ak;
      k2 += __shfl_xor(k2, 1); k2 += __shfl_xor(k2, 2); k2 += __shfl_xor(k2, 4);
      kn2max = fmaxf(kn2max, k2);
    }
    __syncthreads();
  }

  // Cauchy-Schwarz logit upper bound mhat = max|q| * max|k|
  int wid = t >> 6, lane = t & 63;
  {
    float qm = wmax64(qn2max), km = wmax64(kn2max);
    if (lane == 0) { pool[RED_OFF + wid] = qm; pool[RED_OFF + 8 + wid] = km; }
  }
  __syncthreads();
  float qn2 = pool[RED_OFF], kn2 = pool[RED_OFF + 8];
  #pragma unroll
  for (int i = 1; i < 8; ++i) {
    qn2 = fmaxf(qn2, pool[RED_OFF + i]);
    kn2 = fmaxf(kn2, pool[RED_OFF + 8 + i]);
  }
  float mhat = sqrtf(qn2 * kn2);
  __syncthreads();

  // ---- main pass: wave j covers q in [j*128, j*128+128); lane owns 4 keys ----
  int j = wid, kg = lane;
  float kr[4][8], pjm[4];
  #pragma unroll
  for (int kk = 0; kk < 4; ++kk) {
    #pragma unroll
    for (int dd = 0; dd < 8; ++dd) kr[kk][dd] = pool[KS_OFF + (kg*4+kk)*8 + dd];
    pjm[kk] = ((protok[b*LSEQ + kc*256 + kg*4 + kk] != 0) ? 0.f : -1.0e9f) - mhat;
  }

  float acc[4][8] = {};
  float st = 0.f, mu_sh = -3.0e38f;
  int q0 = j * 128;
  for (int q = q0; q < q0 + 128; ++q) {
    float4 a  = *(const float4*)&pool[QS_OFF + q*8];
    float4 b4 = *(const float4*)&pool[QS_OFF + q*8 + 4];
    float4 c0 = *(const float4*)&pool[VS_OFF + q*8];
    float4 c1 = *(const float4*)&pool[VS_OFF + q*8 + 4];
    float qv[8] = {a.x,a.y,a.z,a.w,b4.x,b4.y,b4.z,b4.w};
    float vv[8] = {c0.x,c0.y,c0.z,c0.w,c1.x,c1.y,c1.z,c1.w};
    #pragma unroll
    for (int kk = 0; kk < 4; ++kk) {
      float d = pjm[kk];
      #pragma unroll
      for (int dd = 0; dd < 8; ++dd) d = fmaf(qv[dd], kr[kk][dd], d);
      mu_sh = fmaxf(mu_sh, d);
      float e = __expf(d);
      st += e;
      #pragma unroll
      for (int dd = 0; dd < 8; ++dd) acc[kk][dd] = fmaf(e, vv[dd], acc[kk][dd]);
    }
  }
  __syncthreads();

  // block reductions: true max (shifted) and exp-sum
  {
    float mw = wmax64(mu_sh), sw = wsum64(st);
    if (lane == 0) { pool[RED_OFF + wid] = mw; pool[RED_OFF + 8 + wid] = sw; }
  }
  __syncthreads();
  if (t == 0) {
    float m = pool[RED_OFF];
    float s = pool[RED_OFF + 8];
    #pragma unroll
    for (int i = 1; i < 8; ++i) {
      m = fmaxf(m, pool[RED_OFF + i]);
      s += pool[RED_OFF + 8 + i];
    }
    s_out[blk] = s; mh_out[blk] = mhat; mt_out[blk] = m + mhat;
  }
  __syncthreads();

  // ---- merge acc across the 8 waves (stride-33 rows: bank = (kg+i)%32, conflict-free) ----
  #pragma unroll
  for (int kk = 0; kk < 4; ++kk)
    #pragma unroll
    for (int dd = 0; dd < 8; ++dd)
      pool[j*2112 + kg*33 + kk*8 + dd] = acc[kk][dd];
  __syncthreads();
  float o4[4];
  #pragma unroll
  for (int c = 0; c < 4; ++c) {
    int e = t*4 + c;
    int kg2 = e >> 5, i2 = e & 31;
    float s = 0.f;
    #pragma unroll
    for (int jj2 = 0; jj2 < 8; ++jj2) s += pool[jj2*2112 + kg2*33 + i2];
    o4[c] = s;
  }
  int k = t >> 1, d0 = (t & 1) * 4;
  float* dst = &part[((size_t)(b*LSEQ + kc*256 + k))*DM + h*8 + d0];
  *(float4*)dst = make_float4(o4[0], o4[1], o4[2], o4[3]);
}

// ---- combine: per bh true max + S; cs[kc][bh] ----
__global__ void attn_combine(const float* __restrict__ mh, const float* __restrict__ mt,
                             const float* __restrict__ sp, const float* __restrict__ nz,
                             float* __restrict__ cs){
  int bh = threadIdx.x;
  float mhl[4], sl[4];
  float mu = -3.0e38f;
  #pragma unroll
  for (int i = 0; i < 4; ++i) {
    mhl[i] = mh[bh*4+i]; sl[i] = sp[bh*4+i];
    mu = fmaxf(mu, mt[bh*4+i]);
  }
  float S = 0.f;
  #pragma unroll
  for (int i = 0; i < 4; ++i) S += sl[i] * __expf(mhl[i] - mu);
  float w = nz[bh >> 3] / S;
  float gm = wmax64(w);
  float c = w / gm;
  #pragma unroll
  for (int i = 0; i < 4; ++i) cs[i*64 + bh] = c * __expf(mhl[i] - mu);
}

// ---- O-proj + residual + LN1 (8 rows/block); po: part in, out1 out ----
__global__ __launch_bounds__(512) void oproj_ln(
    float* po, const float* __restrict__ cs,
    const float* __restrict__ Wo, const float* __restrict__ bo,
    const float* __restrict__ xin, const float* __restrict__ g,
    const float* __restrict__ be, const int* __restrict__ protok)
{
  int tid = threadIdx.x, rl = tid >> 6, c = tid & 63;
  int r = blockIdx.x * 8 + rl;
  int bh = ((r >> 10) << 3) + (c >> 3);
  int kc = (r >> 8) & 3;
  __shared__ float As[8][64];
  As[rl][c] = po[(size_t)r * DM + c] * cs[kc*64 + bh];
  __syncthreads();
  float acc = bo[c];
  #pragma unroll
  for (int jj = 0; jj < DM; ++jj) acc = fmaf(As[rl][jj], Wo[jj * DM + c], acc);
  float keep = (protok[r] != 0) ? 1.f : 0.f;
  float v = xin[(size_t)r * DM + c] + acc * keep;
  float mu = wsum64(v) * 0.015625f;
  float d = v - mu;
  float var = wsum64(d * d) * 0.015625f;
  float o = d * rsqrtf(var + 1e-9f) * g[c] + be[c];
  po[(size_t)r * DM + c] = o * keep;
}

// ---- fused FFN + residual + LN2 (8 rows/block) ----
__global__ __launch_bounds__(512) void ffn_ln(
    const float* __restrict__ out1,
    const float* __restrict__ W1, const float* __restrict__ b1,
    const float* __restrict__ W2, const float* __restrict__ b2,
    const float* __restrict__ g, const float* __restrict__ be,
    const int* __restrict__ protok, float* __restrict__ xout)
{
  int tid = threadIdx.x, rl = tid >> 6, c = tid & 63;
  int r = blockIdx.x * 8 + rl;
  __shared__ float xs[8][64];
  __shared__ float h1s[8][DFF];
  xs[rl][c] = out1[(size_t)r * DM + c];
  __syncthreads();
  #pragma unroll
  for (int s = 0; s < 4; ++s) {
    int col = c + 64 * s;
    float a = b1[col];
    #pragma unroll
    for (int jj = 0; jj < DM; ++jj) a = fmaf(xs[rl][jj], W1[jj * DFF + col], a);
    h1s[rl][col] = fmaxf(a, 0.f);
  }
  __syncthreads();
  float a2 = b2[c];
  #pragma unroll 8
  for (int jj = 0; jj < DFF; ++jj) a2 = fmaf(h1s[rl][jj], W2[jj * DM + c], a2);
  float keep = (protok[r] != 0) ? 1.f : 0.f;
  float v = xs[rl][c] + a2 * keep;
  float mu = wsum64(v) * 0.015625f;
  float d = v - mu;
  float var = wsum64(d * d) * 0.015625f;
  float o = d * rsqrtf(var + 1e-9f) * g[c] + be[c];
  xout[(size_t)r * DM + c] = o * keep;
}

extern "C" void kernel_launch(void* const* d_in, const int* in_sizes, int n_in,
                              void* d_out, int out_size, void* d_ws, size_t ws_size,
                              hipStream_t stream) {
  const float* x      = (const float*)d_in[0];
  const int*   protok = (const int*)d_in[1];
  const float* Wq = (const float*)d_in[2];  const float* bq = (const float*)d_in[3];
  const float* Wk = (const float*)d_in[4];  const float* bk = (const float*)d_in[5];
  const float* Wv = (const float*)d_in[6];  const float* bv = (const float*)d_in[7];
  const float* Wo = (const float*)d_in[8];  const float* bo = (const float*)d_in[9];
  const float* W1 = (const float*)d_in[10]; const float* b1 = (const float*)d_in[11];
  const float* W2 = (const float*)d_in[12]; const float* b2 = (const float*)d_in[13];
  const float* g1 = (const float*)d_in[14]; const float* be1 = (const float*)d_in[15];
  const float* g2 = (const float*)d_in[16]; const float* be2 = (const float*)d_in[17];

  const size_t N = (size_t)NROW * DM;   // 524288
  float* xf   = (float*)d_ws;           // N
  float* po   = xf + N;                 // N (attn part -> out1, aliased)
  float* nzb  = po + N;                 // 8
  float* mh   = nzb + 8;                // 256
  float* mt   = mh + 256;               // 256
  float* sp   = mt + 256;               // 256
  float* cs   = sp + 256;               // 256
  // ws use: 2N + ~1K floats ~= 4.2 MB

  nz_kernel<<<NB, 1024, 0, stream>>>(protok, nzb);

  for (int l = 0; l < NLAYER; ++l) {
    const float* Wq_l = Wq + (size_t)l * DM * DM;  const float* bq_l = bq + (size_t)l * DM;
    const float* Wk_l = Wk + (size_t)l * DM * DM;  const float* bk_l = bk + (size_t)l * DM;
    const float* Wv_l = Wv + (size_t)l * DM * DM;  const float* bv_l = bv + (size_t)l * DM;
    const float* Wo_l = Wo + (size_t)l * DM * DM;  const float* bo_l = bo + (size_t)l * DM;
    const float* W1_l = W1 + (size_t)l * DM * DFF; const float* b1_l = b1 + (size_t)l * DFF;
    const float* W2_l = W2 + (size_t)l * DFF * DM; const float* b2_l = b2 + (size_t)l * DM;
    const float* g1_l = g1 + (size_t)l * DM;  const float* be1_l = be1 + (size_t)l * DM;
    const float* g2_l = g2 + (size_t)l * DM;  const float* be2_l = be2 + (size_t)l * DM;

    const float* xin = (l == 0) ? x : xf;
    float* xout = (l == NLAYER - 1) ? (float*)d_out : xf;

    qkv_attn<<<256, 512, 0, stream>>>(xin, protok, Wq_l, bq_l, Wk_l, bk_l, Wv_l, bv_l,
                                      po, mh, mt, sp);
    attn_combine<<<1, 64, 0, stream>>>(mh, mt, sp, nzb, cs);
    oproj_ln<<<NROW / 8, 512, 0, stream>>>(po, cs, Wo_l, bo_l, xin, g1_l, be1_l, protok);
    ffn_ln<<<NROW / 8, 512, 0, stream>>>(po, W1_l, b1_l, W2_l, b2_l, g2_l, be2_l, protok, xout);
  }
}